// Round 9
// baseline (309.079 us; speedup 1.0000x reference)
//
#include <hip/hip_runtime.h>
#include <cstdint>
#include <cstddef>

#define B_    8
#define N_    2048
#define FIN   128
#define FOUT  64
#define ALPHA 0.2f
#define LOG2E 1.4426950408889634f

typedef __attribute__((ext_vector_type(8))) _Float16 half8;
typedef __attribute__((ext_vector_type(4))) _Float16 half4;
typedef __attribute__((ext_vector_type(4))) float float4v;

// ---------------------------------------------------------------------------
// Single fused kernel, grid 1024, block 256 (4 blocks/CU needed; LDS 30.3 KB
// -> 5/CU, VGPR<=128 -> 8/CU, so full grid co-resident with margin).
// Block (b, i0) owns rows i0..i0+15 of batch b.
//  Phase 1a: wh = x @ W via MFMA (split-fp16 compensation, fp32-accurate),
//            whT fp16, s1 = wh@a1, s2 = wh@a2.
//  Phase 1b: pack the SAME 16 adj rows -> LDS bitmask.
//  BATCH barrier: device-scope atomic counter bar[b] (zeroed via memsetAsync
//  before launch); agent-scope ACQ_REL/ACQUIRE gives cross-XCD visibility
//  of whT/s1/s2 (Guideline 16). Batch-scoped -> early batches start phase 2
//  while later batches still stream adj.
//  Phase 2:  pipelined masked-softmax + PV MFMA, masks from LDS.
// ---------------------------------------------------------------------------
__global__ __launch_bounds__(256, 4) void kfused(
    const float* __restrict__ x, const int* __restrict__ adj,
    const float* __restrict__ W, const float* __restrict__ w2,
    _Float16* __restrict__ whT, float* __restrict__ s1, float* __restrict__ s2,
    unsigned* __restrict__ bar, float* __restrict__ out)
{
    __shared__ __attribute__((aligned(16))) _Float16 xth[16][136];
    __shared__ __attribute__((aligned(16))) _Float16 xtl[16][136];
    __shared__ float s1p[4][16];
    __shared__ float s2p[4][16];
    __shared__ __attribute__((aligned(16))) unsigned long long maskS[16][32];
    __shared__ __attribute__((aligned(16))) _Float16 pT[2][16][264];
    __shared__ float lL[16];
    __shared__ float smaxL[4];

    int t = threadIdx.x, lane = t & 63, w = t >> 6;
    int blk = blockIdx.x;
    int b = blk >> 7;
    int i0 = (blk & 127) << 4;
    int l15 = lane & 15, quad = lane >> 4;
    int f0 = w * 16;

    // ---------------- phase 1a: stage x tile (16x128 fp32), hi/lo split ----
    const float* xb = x + ((size_t)b * N_ + i0) * FIN;
    #pragma unroll
    for (int j = 0; j < 2; ++j) {
        int idx = t + j * 256;                // 512 float4s, coalesced
        int row = idx >> 5;
        int k0 = (idx & 31) * 4;
        float4 v = ((const float4*)xb)[idx];
        float vv[4] = {v.x, v.y, v.z, v.w};
        half4 h, l;
        #pragma unroll
        for (int e = 0; e < 4; ++e) {
            _Float16 hi = (_Float16)vv[e];
            h[e] = hi;
            l[e] = (_Float16)(vv[e] - (float)hi);
        }
        *(half4*)&xth[row][k0] = h;
        *(half4*)&xtl[row][k0] = l;
    }
    __syncthreads();

    // B fragments inline from fp32 W (L2-hot): k = c*32 + quad*8 + e
    {
        half8 bh[4], bl[4];
        const float* wcol = W + (f0 + l15);
        #pragma unroll
        for (int c = 0; c < 4; ++c) {
            #pragma unroll
            for (int e = 0; e < 8; ++e) {
                float v = wcol[(size_t)(c * 32 + quad * 8 + e) * FOUT];
                _Float16 hi = (_Float16)v;
                bh[c][e] = hi;
                bl[c][e] = (_Float16)(v - (float)hi);
            }
        }
        float a1f = w2[f0 + l15], a2f = w2[FOUT + f0 + l15];

        float4v acc1 = {0.f, 0.f, 0.f, 0.f};
        #pragma unroll
        for (int c = 0; c < 4; ++c) {
            half8 ah = *(const half8*)&xth[l15][c * 32 + quad * 8];
            half8 al = *(const half8*)&xtl[l15][c * 32 + quad * 8];
            acc1 = __builtin_amdgcn_mfma_f32_16x16x32_f16(ah, bh[c], acc1, 0, 0, 0);
            acc1 = __builtin_amdgcn_mfma_f32_16x16x32_f16(ah, bl[c], acc1, 0, 0, 0);
            acc1 = __builtin_amdgcn_mfma_f32_16x16x32_f16(al, bh[c], acc1, 0, 0, 0);
        }
        // D: col = f0+l15, row = quad*4+reg (4 consecutive j -> 8B store)
        half4 hv;
        #pragma unroll
        for (int reg = 0; reg < 4; ++reg) hv[reg] = (_Float16)acc1[reg];
        *(half4*)(whT + ((size_t)b * FOUT + f0 + l15) * N_ + i0 + quad * 4) = hv;

        // s1/s2 partials: reduce over 16 features (l15) per row
        #pragma unroll
        for (int reg = 0; reg < 4; ++reg) {
            float v1 = acc1[reg] * a1f;
            float v2 = acc1[reg] * a2f;
            #pragma unroll
            for (int m = 1; m <= 8; m <<= 1) {
                v1 += __shfl_xor(v1, m);
                v2 += __shfl_xor(v2, m);
            }
            if (l15 == 0) {
                s1p[w][quad * 4 + reg] = v1;
                s2p[w][quad * 4 + reg] = v2;
            }
        }
    }
    __syncthreads();
    if (t < 16) {
        s1[(size_t)b * N_ + i0 + t] = s1p[0][t] + s1p[1][t] + s1p[2][t] + s1p[3][t];
    } else if (t < 32) {
        int r = t - 16;
        s2[(size_t)b * N_ + i0 + r] = s2p[0][r] + s2p[1][r] + s2p[2][r] + s2p[3][r];
    }

    // ---------------- phase 1b: pack 4 adj rows/wave -> LDS bitmask --------
    {
        size_t growbase = (size_t)b * N_ + i0 + (size_t)w * 4;
        #pragma unroll 1
        for (int r = 0; r < 4; ++r) {
            const int* rp = adj + (growbase + r) * N_ + lane;
            int a[32];
            #pragma unroll
            for (int it = 0; it < 32; ++it) a[it] = rp[it * 64];  // 32 in flight
            #pragma unroll
            for (int it = 0; it < 32; ++it) {
                unsigned long long m = __ballot(a[it] > 0);
                if (lane == 0) maskS[w * 4 + r][it] = m;
            }
        }
    }

    // ---- batch-scope barrier: all 128 blocks of batch b finished phase 1 --
    __syncthreads();                          // all waves' stores issued
    if (t == 0) {
        // release: drains vmcnt + L2 writeback (agent scope), then count
        __hip_atomic_fetch_add(&bar[b], 1u, __ATOMIC_ACQ_REL,
                               __HIP_MEMORY_SCOPE_AGENT);
        while (__hip_atomic_load(&bar[b], __ATOMIC_ACQUIRE,
                                 __HIP_MEMORY_SCOPE_AGENT) < 128u)
            __builtin_amdgcn_s_sleep(2);
    }
    __syncthreads();                          // all threads see fresh data

    // ---------------- phase 2: masked softmax + PV (R6 pipeline) ----------
    // exact S2MAX over batch b (8 KB, L2-hot)
    const float4* s2v = (const float4*)(s2 + (size_t)b * N_);
    float4 ua_ = s2v[t], ub_ = s2v[t + 256];
    float vm = fmaxf(fmaxf(fmaxf(ua_.x, ua_.y), fmaxf(ua_.z, ua_.w)),
                     fmaxf(fmaxf(ub_.x, ub_.y), fmaxf(ub_.z, ub_.w)));
    #pragma unroll
    for (int m = 32; m >= 1; m >>= 1) vm = fmaxf(vm, __shfl_xor(vm, m));
    if (lane == 0) smaxL[w] = vm;
    __syncthreads();
    float s2max = fmaxf(fmaxf(smaxL[0], smaxL[1]), fmaxf(smaxL[2], smaxL[3]));

    int shn = (lane & 7) * 4;
    int oct = lane >> 3;

    float c1[4], c2[4], lacc[4];
    #pragma unroll
    for (int rr = 0; rr < 4; ++rr) {
        float sv = s1[(size_t)b * N_ + i0 + w * 4 + rr];   // wave-uniform, own block
        float mm = sv + s2max;
        float mh = fmaxf(mm, ALPHA * mm);    // leaky(s1_i + s2max) >= row max
        c1[rr] = (sv - mh) * LOG2E;
        c2[rr] = (ALPHA * sv - mh) * LOG2E;
        lacc[rr] = 0.f;
    }

    // masks from LDS: rows w*4.., 64 u32 per row
    const unsigned* mSL = (const unsigned*)&maskS[w * 4][0];
    const float* s2L = s2 + (size_t)b * N_ + lane * 4;
    const _Float16* wB = whT + ((size_t)b * FOUT + f0 + l15) * N_ + quad * 8;

    float4v acc = {0.f, 0.f, 0.f, 0.f};
    unsigned mb0[4], mb1[4];
    float4 sv0, sv1;
    half8 bfr[8];

#define LOADMS(cc, MB, SV) do {                                              \
        _Pragma("unroll")                                                    \
        for (int rr_ = 0; rr_ < 4; ++rr_)                                    \
            MB[rr_] = mSL[rr_ * 64 + (cc) * 8 + oct];                        \
        SV = *(const float4*)(s2L + (cc) * 256);                             \
    } while (0)

#define LOADBF(cc) do {                                                      \
        const _Float16* wp_ = wB + (cc) * 256;                               \
        _Pragma("unroll")                                                    \
        for (int kk_ = 0; kk_ < 8; ++kk_)                                    \
            bfr[kk_] = *(const half8*)(wp_ + kk_ * 32);                      \
    } while (0)

#define PCOMP(MB, SV, PB) do {                                               \
        float u_[4]  = {SV.x * LOG2E, SV.y * LOG2E, SV.z * LOG2E, SV.w * LOG2E}; \
        float ua2_[4] = {u_[0] * ALPHA, u_[1] * ALPHA, u_[2] * ALPHA, u_[3] * ALPHA}; \
        _Pragma("unroll")                                                    \
        for (int rr_ = 0; rr_ < 4; ++rr_) {                                  \
            unsigned mbits_ = (MB[rr_] >> shn) & 0xFu;                       \
            half4 pf_;                                                       \
            float ls_ = 0.f;                                                 \
            _Pragma("unroll")                                                \
            for (int e_ = 0; e_ < 4; ++e_) {                                 \
                float tt_ = fmaxf(c1[rr_] + u_[e_], c2[rr_] + ua2_[e_]);     \
                float p_ = __builtin_amdgcn_exp2f(tt_);                      \
                p_ = (mbits_ & (1u << e_)) ? p_ : 0.f;                       \
                ls_ += p_;                                                   \
                pf_[e_] = (_Float16)p_;                                      \
            }                                                                \
            lacc[rr_] += ls_;                                                \
            *(half4*)&pT[PB][w * 4 + rr_][lane * 4] = pf_;                   \
        }                                                                    \
    } while (0)

#define MFMA8(PB) do {                                                       \
        _Pragma("unroll")                                                    \
        for (int kk_ = 0; kk_ < 8; ++kk_) {                                  \
            half8 af_ = *(const half8*)&pT[PB][l15][kk_ * 32 + quad * 8];    \
            acc = __builtin_amdgcn_mfma_f32_16x16x32_f16(af_, bfr[kk_], acc, 0, 0, 0); \
        }                                                                    \
    } while (0)

    LOADMS(0, mb0, sv0);                       // prologue

    #pragma unroll 1
    for (int c = 0; c < 8; c += 2) {
        LOADBF(c);
        LOADMS(c + 1, mb1, sv1);
        PCOMP(mb0, sv0, 0);
        __syncthreads();                       // publish pT[0]
        MFMA8(0);
        LOADBF(c + 1);
        if (c < 6) LOADMS(c + 2, mb0, sv0);
        PCOMP(mb1, sv1, 1);
        if (c == 6) {                          // publish row sums (last chunk)
            #pragma unroll
            for (int rr = 0; rr < 4; ++rr) {
                float v = lacc[rr];
                #pragma unroll
                for (int m = 32; m >= 1; m >>= 1) v += __shfl_xor(v, m);
                if (lane == 0) lL[w * 4 + rr] = v;
            }
        }
        __syncthreads();                       // publish pT[1]
        MFMA8(1);
    }
#undef LOADMS
#undef LOADBF
#undef PCOMP
#undef MFMA8

    // epilogue: normalize, ELU, store. D: row=quad*4+reg, col=f0+l15
    #pragma unroll
    for (int reg = 0; reg < 4; ++reg) {
        int row = quad * 4 + reg;
        float val = acc[reg] / lL[row];
        val = (val > 0.f) ? val : (__expf(val) - 1.f);   // ELU
        out[((size_t)b * N_ + i0 + row) * FOUT + f0 + l15] = val;
    }
}

// ---------------------------------------------------------------------------
extern "C" void kernel_launch(void* const* d_in, const int* in_sizes, int n_in,
                              void* d_out, int out_size, void* d_ws, size_t ws_size,
                              hipStream_t stream) {
    const float* x   = (const float*)d_in[0];
    const int*   adj = (const int*)d_in[1];
    const float* W   = (const float*)d_in[2];
    const float* w2  = (const float*)d_in[3];
    float* out = (float*)d_out;

    char* ws = (char*)d_ws;
    _Float16* whT = (_Float16*)ws;                              // 2 MiB
    float* s1  = (float*)(ws + 2097152);                        // 64 KiB
    float* s2  = (float*)(ws + 2097152 + 65536);                // 64 KiB
    unsigned* bar = (unsigned*)(ws + 2097152 + 131072);         // 32 B

    hipMemsetAsync(bar, 0, 8 * sizeof(unsigned), stream);       // zero barrier
    kfused<<<(B_ * N_) / 16, 256, 0, stream>>>(x, adj, W, w2, whT, s1, s2, bar, out);
}

// Round 10
// 247.820 us; speedup vs baseline: 1.2472x; 1.2472x over previous
//
#include <hip/hip_runtime.h>
#include <cstdint>
#include <cstddef>

#define B_    8
#define N_    2048
#define FIN   128
#define FOUT  64
#define ALPHA 0.2f
#define LOG2E 1.4426950408889634f

typedef __attribute__((ext_vector_type(8))) _Float16 half8;
typedef __attribute__((ext_vector_type(4))) _Float16 half4;
typedef __attribute__((ext_vector_type(4))) float float4v;

// ---------------------------------------------------------------------------
// Kernel 1 (fused, unchanged from R6 -- proven correct): per block
// (b, r0..r0+31): wh = x @ W via MFMA (split-fp16 compensation), whT fp16,
// s1 = wh@a1, s2 = wh@a2, and pack the block's 32 adj rows -> bitmask.
// ---------------------------------------------------------------------------
__global__ __launch_bounds__(256, 2) void k1_wh(
    const float* __restrict__ x, const float* __restrict__ W,
    const float* __restrict__ w2, const int* __restrict__ adj,
    _Float16* __restrict__ whT, float* __restrict__ s1, float* __restrict__ s2,
    unsigned long long* __restrict__ maskp)
{
    __shared__ __attribute__((aligned(16))) _Float16 xth[32][136];
    __shared__ __attribute__((aligned(16))) _Float16 xtl[32][136];
    __shared__ float s1p[4][32];
    __shared__ float s2p[4][32];

    int t = threadIdx.x, lane = t & 63, w = t >> 6;
    int b = blockIdx.x >> 6;
    int r0 = (blockIdx.x & 63) << 5;          // 32 rows per block
    const float* xb = x + ((size_t)b * N_ + r0) * FIN;

    #pragma unroll
    for (int j = 0; j < 4; ++j) {
        int idx = t + j * 256;
        int row = idx >> 5;
        int k0 = (idx & 31) * 4;
        float4 v = ((const float4*)xb)[idx];
        float vv[4] = {v.x, v.y, v.z, v.w};
        half4 h, l;
        #pragma unroll
        for (int e = 0; e < 4; ++e) {
            _Float16 hi = (_Float16)vv[e];
            h[e] = hi;
            l[e] = (_Float16)(vv[e] - (float)hi);
        }
        *(half4*)&xth[row][k0] = h;
        *(half4*)&xtl[row][k0] = l;
    }
    __syncthreads();

    int l15 = lane & 15, quad = lane >> 4;
    int f0 = w * 16;

    half8 bh[4], bl[4];
    const float* wcol = W + (f0 + l15);
    #pragma unroll
    for (int c = 0; c < 4; ++c) {
        #pragma unroll
        for (int e = 0; e < 8; ++e) {
            float v = wcol[(size_t)(c * 32 + quad * 8 + e) * FOUT];
            _Float16 hi = (_Float16)v;
            bh[c][e] = hi;
            bl[c][e] = (_Float16)(v - (float)hi);
        }
    }
    float a1f = w2[f0 + l15], a2f = w2[FOUT + f0 + l15];

    #pragma unroll
    for (int rt = 0; rt < 2; ++rt) {
        float4v acc = {0.f, 0.f, 0.f, 0.f};
        #pragma unroll
        for (int c = 0; c < 4; ++c) {
            half8 ah = *(const half8*)&xth[rt * 16 + l15][c * 32 + quad * 8];
            half8 al = *(const half8*)&xtl[rt * 16 + l15][c * 32 + quad * 8];
            acc = __builtin_amdgcn_mfma_f32_16x16x32_f16(ah, bh[c], acc, 0, 0, 0);
            acc = __builtin_amdgcn_mfma_f32_16x16x32_f16(ah, bl[c], acc, 0, 0, 0);
            acc = __builtin_amdgcn_mfma_f32_16x16x32_f16(al, bh[c], acc, 0, 0, 0);
        }
        half4 hv;
        #pragma unroll
        for (int reg = 0; reg < 4; ++reg) hv[reg] = (_Float16)acc[reg];
        *(half4*)(whT + ((size_t)b * FOUT + f0 + l15) * N_ + r0 + rt * 16 + quad * 4) = hv;

        #pragma unroll
        for (int reg = 0; reg < 4; ++reg) {
            float v1 = acc[reg] * a1f;
            float v2 = acc[reg] * a2f;
            #pragma unroll
            for (int m = 1; m <= 8; m <<= 1) {
                v1 += __shfl_xor(v1, m);
                v2 += __shfl_xor(v2, m);
            }
            if (l15 == 0) {
                s1p[w][rt * 16 + quad * 4 + reg] = v1;
                s2p[w][rt * 16 + quad * 4 + reg] = v2;
            }
        }
    }
    __syncthreads();
    if (t < 32) {
        float v = s1p[0][t] + s1p[1][t] + s1p[2][t] + s1p[3][t];
        s1[(size_t)b * N_ + r0 + t] = v;
    } else if (t < 64) {
        int r = t - 32;
        float v = s2p[0][r] + s2p[1][r] + s2p[2][r] + s2p[3][r];
        s2[(size_t)b * N_ + r0 + r] = v;
    }

    size_t growbase = (size_t)b * N_ + r0 + (size_t)w * 8;
    #pragma unroll 1
    for (int r = 0; r < 8; ++r) {
        const int* rp = adj + (growbase + r) * N_ + lane;
        unsigned long long* orow = maskp + (growbase + r) * 32;
        int a[32];
        #pragma unroll
        for (int it = 0; it < 32; ++it) a[it] = rp[it * 64];  // 32 loads in flight
        #pragma unroll
        for (int it = 0; it < 32; ++it) {
            unsigned long long m = __ballot(a[it] > 0);
            if (lane == 0) orow[it] = m;
        }
    }
}

// ---------------------------------------------------------------------------
// Kernel 2: WAVE-PRIVATE masked softmax + PV. Zero barriers / zero LDS in
// the main loop (the m233-style 2-phase barrier structure was the measured
// ~85%-idle cost; VALUBusy*dur matched the work model in every variant).
// Each wave owns the block's 16 rows for cols [w*512, w*512+512).
// Lane (l15,quad) computes P(row=l15, col=quad*8+e) per 32-col k-step --
// EXACTLY the MFMA A-fragment layout, so P goes straight from registers
// into the MFMA. 16 k-steps/wave, 4 feature-group MFMAs each.
// End: one barrier; acc/rowsum merge via LDS (17-pad -> conflict-free).
// ---------------------------------------------------------------------------
__global__ __launch_bounds__(256, 4) void k2_attn(
    const unsigned* __restrict__ mask32, const _Float16* __restrict__ whT,
    const float* __restrict__ s1, const float* __restrict__ s2,
    float* __restrict__ out)
{
    __shared__ float accL[4][64][17];   // [wave][lane][fgroup*4+reg], pad 17
    __shared__ float laccL[4][16];      // [wave][row]

    int t = threadIdx.x, lane = t & 63, w = t >> 6;
    int b = blockIdx.x >> 7;
    int i0 = (blockIdx.x & 127) << 4;
    int l15 = lane & 15, quad = lane >> 4;

    // s2max over batch b: per-wave (8 KB L2-hot), no block barrier needed
    const float4* s2v = (const float4*)(s2 + (size_t)b * N_);
    float vm = -1e30f;
    #pragma unroll
    for (int j = 0; j < 8; ++j) {
        float4 v = s2v[lane + j * 64];
        vm = fmaxf(vm, fmaxf(fmaxf(v.x, v.y), fmaxf(v.z, v.w)));
    }
    #pragma unroll
    for (int m = 32; m >= 1; m >>= 1) vm = fmaxf(vm, __shfl_xor(vm, m));
    float s2max = vm;

    // per-lane row constants (this lane's row = l15)
    float sv = s1[(size_t)b * N_ + i0 + l15];
    float mm = sv + s2max;
    float mh = fmaxf(mm, ALPHA * mm);          // leaky(s1_i + s2max) >= row max
    float c1 = (sv - mh) * LOG2E;
    float c2 = (ALPHA * sv - mh) * LOG2E;
    float lacc = 0.f;

    // bases: this wave's column range = [w*512, w*512+512)
    // mask u32 word (w*16+ks) of row (i0+l15) = cols [w*512+ks*32, +32)
    const unsigned* mRow = mask32 + ((size_t)b * N_ + i0 + l15) * 64 + w * 16;
    const float* s2base = s2 + (size_t)b * N_ + w * 512 + quad * 8;
    const _Float16* wBb = whT + ((size_t)b * FOUT + l15) * N_ + w * 512 + quad * 8;

    float4v acc0 = {0.f,0.f,0.f,0.f}, acc1 = {0.f,0.f,0.f,0.f};
    float4v acc2 = {0.f,0.f,0.f,0.f}, acc3 = {0.f,0.f,0.f,0.f};

    #pragma unroll 1
    for (int ks = 0; ks < 16; ++ks) {
        unsigned mw = mRow[ks];
        unsigned mby = (mw >> (quad * 8)) & 0xFFu;   // 8 mask bits, cols e=0..7
        const float* sp = s2base + ks * 32;
        float4 sa = *(const float4*)sp;
        float4 sb = *(const float4*)(sp + 4);
        const _Float16* wp = wBb + ks * 32;
        half8 b0 = *(const half8*)(wp);
        half8 b1 = *(const half8*)(wp + (size_t)16 * N_);
        half8 b2 = *(const half8*)(wp + (size_t)32 * N_);
        half8 b3 = *(const half8*)(wp + (size_t)48 * N_);

        float ss[8] = {sa.x, sa.y, sa.z, sa.w, sb.x, sb.y, sb.z, sb.w};
        half8 pa;
        float ls = 0.f;
        #pragma unroll
        for (int e = 0; e < 8; ++e) {
            float u = ss[e] * LOG2E;
            float tt = fmaxf(c1 + u, c2 + u * ALPHA);  // leaky-mh, log2e folded
#if __has_builtin(__builtin_amdgcn_exp2f)
            float p = __builtin_amdgcn_exp2f(tt);
#else
            float p = exp2f(tt);
#endif
            p = (mby & (1u << e)) ? p : 0.f;           // mask -> exact 0
            ls += p;
            pa[e] = (_Float16)p;
        }
        lacc += ls;

        // P already in A-frag layout: row=l15, k=quad*8+e. B: k=quad*8+e, col=l15.
        acc0 = __builtin_amdgcn_mfma_f32_16x16x32_f16(pa, b0, acc0, 0, 0, 0);
        acc1 = __builtin_amdgcn_mfma_f32_16x16x32_f16(pa, b1, acc1, 0, 0, 0);
        acc2 = __builtin_amdgcn_mfma_f32_16x16x32_f16(pa, b2, acc2, 0, 0, 0);
        acc3 = __builtin_amdgcn_mfma_f32_16x16x32_f16(pa, b3, acc3, 0, 0, 0);
    }

    // row-sum partial: reduce across the 4 quads (lanes sharing l15)
    lacc += __shfl_xor(lacc, 16);
    lacc += __shfl_xor(lacc, 32);
    if (lane < 16) laccL[w][lane] = lacc;
    #pragma unroll
    for (int reg = 0; reg < 4; ++reg) {
        accL[w][lane][reg]      = acc0[reg];
        accL[w][lane][4 + reg]  = acc1[reg];
        accL[w][lane][8 + reg]  = acc2[reg];
        accL[w][lane][12 + reg] = acc3[reg];
    }
    __syncthreads();    // the ONLY block barrier

    // epilogue: wave w handles feature group w. D: row=quad*4+reg, col=l15.
    #pragma unroll
    for (int reg = 0; reg < 4; ++reg) {
        int row = quad * 4 + reg;
        int idx = w * 4 + reg;
        float v = accL[0][lane][idx] + accL[1][lane][idx]
                + accL[2][lane][idx] + accL[3][lane][idx];
        float ssum = laccL[0][row] + laccL[1][row]
                   + laccL[2][row] + laccL[3][row];
        float val = v / ssum;
        val = (val > 0.f) ? val : (__expf(val) - 1.f);   // ELU
        out[((size_t)b * N_ + i0 + row) * FOUT + w * 16 + l15] = val;
    }
}

// ---------------------------------------------------------------------------
extern "C" void kernel_launch(void* const* d_in, const int* in_sizes, int n_in,
                              void* d_out, int out_size, void* d_ws, size_t ws_size,
                              hipStream_t stream) {
    const float* x   = (const float*)d_in[0];
    const int*   adj = (const int*)d_in[1];
    const float* W   = (const float*)d_in[2];
    const float* w2  = (const float*)d_in[3];
    float* out = (float*)d_out;

    char* ws = (char*)d_ws;
    _Float16* whT = (_Float16*)ws;                              // 2 MiB
    float* s1  = (float*)(ws + 2097152);                        // 64 KiB
    float* s2  = (float*)(ws + 2097152 + 65536);                // 64 KiB
    unsigned long long* maskp =
        (unsigned long long*)(ws + 2097152 + 131072);           // 4 MiB

    k1_wh<<<(B_ * N_) / 32, 256, 0, stream>>>(x, W, w2, adj, whT, s1, s2, maskp);
    k2_attn<<<(B_ * N_) / 16, 256, 0, stream>>>((const unsigned*)maskp, whT, s1, s2, out);
}

// Round 11
// 218.961 us; speedup vs baseline: 1.4116x; 1.1318x over previous
//
#include <hip/hip_runtime.h>
#include <cstdint>
#include <cstddef>

#define B_    8
#define N_    2048
#define FIN   128
#define FOUT  64
#define ALPHA 0.2f
#define LOG2E 1.4426950408889634f

typedef __attribute__((ext_vector_type(8))) _Float16 half8;
typedef __attribute__((ext_vector_type(4))) _Float16 half4;
typedef __attribute__((ext_vector_type(4))) float float4v;

// ---------------------------------------------------------------------------
// Kernel 1: wh = x @ W via MFMA (split-fp16 compensation, fp32-level
// accuracy), whT fp16, s1 = wh@a1, s2 = wh@a2. W hi/lo fragments built
// inline from fp32 W (k0 deleted; proven in R6/R9/R10).
// ---------------------------------------------------------------------------
__global__ __launch_bounds__(256, 2) void k1_wh(
    const float* __restrict__ x, const float* __restrict__ W,
    const float* __restrict__ w2,
    _Float16* __restrict__ whT, float* __restrict__ s1, float* __restrict__ s2)
{
    __shared__ __attribute__((aligned(16))) _Float16 xth[32][136];
    __shared__ __attribute__((aligned(16))) _Float16 xtl[32][136];
    __shared__ float s1p[4][32];
    __shared__ float s2p[4][32];

    int t = threadIdx.x, lane = t & 63, w = t >> 6;
    int b = blockIdx.x >> 6;
    int r0 = (blockIdx.x & 63) << 5;          // 32 rows per block
    const float* xb = x + ((size_t)b * N_ + r0) * FIN;

    #pragma unroll
    for (int j = 0; j < 4; ++j) {
        int idx = t + j * 256;
        int row = idx >> 5;
        int k0 = (idx & 31) * 4;
        float4 v = ((const float4*)xb)[idx];
        float vv[4] = {v.x, v.y, v.z, v.w};
        half4 h, l;
        #pragma unroll
        for (int e = 0; e < 4; ++e) {
            _Float16 hi = (_Float16)vv[e];
            h[e] = hi;
            l[e] = (_Float16)(vv[e] - (float)hi);
        }
        *(half4*)&xth[row][k0] = h;
        *(half4*)&xtl[row][k0] = l;
    }
    __syncthreads();

    int l15 = lane & 15, quad = lane >> 4;
    int f0 = w * 16;

    half8 bh[4], bl[4];
    const float* wcol = W + (f0 + l15);
    #pragma unroll
    for (int c = 0; c < 4; ++c) {
        #pragma unroll
        for (int e = 0; e < 8; ++e) {
            float v = wcol[(size_t)(c * 32 + quad * 8 + e) * FOUT];
            _Float16 hi = (_Float16)v;
            bh[c][e] = hi;
            bl[c][e] = (_Float16)(v - (float)hi);
        }
    }
    float a1f = w2[f0 + l15], a2f = w2[FOUT + f0 + l15];

    #pragma unroll
    for (int rt = 0; rt < 2; ++rt) {
        float4v acc = {0.f, 0.f, 0.f, 0.f};
        #pragma unroll
        for (int c = 0; c < 4; ++c) {
            half8 ah = *(const half8*)&xth[rt * 16 + l15][c * 32 + quad * 8];
            half8 al = *(const half8*)&xtl[rt * 16 + l15][c * 32 + quad * 8];
            acc = __builtin_amdgcn_mfma_f32_16x16x32_f16(ah, bh[c], acc, 0, 0, 0);
            acc = __builtin_amdgcn_mfma_f32_16x16x32_f16(ah, bl[c], acc, 0, 0, 0);
            acc = __builtin_amdgcn_mfma_f32_16x16x32_f16(al, bh[c], acc, 0, 0, 0);
        }
        half4 hv;
        #pragma unroll
        for (int reg = 0; reg < 4; ++reg) hv[reg] = (_Float16)acc[reg];
        *(half4*)(whT + ((size_t)b * FOUT + f0 + l15) * N_ + r0 + rt * 16 + quad * 4) = hv;

        #pragma unroll
        for (int reg = 0; reg < 4; ++reg) {
            float v1 = acc[reg] * a1f;
            float v2 = acc[reg] * a2f;
            #pragma unroll
            for (int m = 1; m <= 8; m <<= 1) {
                v1 += __shfl_xor(v1, m);
                v2 += __shfl_xor(v2, m);
            }
            if (l15 == 0) {
                s1p[w][rt * 16 + quad * 4 + reg] = v1;
                s2p[w][rt * 16 + quad * 4 + reg] = v2;
            }
        }
    }
    __syncthreads();
    if (t < 32) {
        float v = s1p[0][t] + s1p[1][t] + s1p[2][t] + s1p[3][t];
        s1[(size_t)b * N_ + r0 + t] = v;
    } else if (t < 64) {
        int r = t - 32;
        float v = s2p[0][r] + s2p[1][r] + s2p[2][r] + s2p[3][r];
        s2[(size_t)b * N_ + r0 + r] = v;
    }
}

// ---------------------------------------------------------------------------
// Kernel 2: R3's DMA flash-attention structure (best measured), widened to
// 32 rows / 512 threads so the dispatch exceeds the 77 us fills and gets a
// full rocprof counter row (visibility-forcing round).
// Waves 0-3 = row-tile 0, waves 4-7 = row-tile 1; per-wave code verbatim R3
// (same 4-DMA+1-s2 stage, same vmcnt(13)/vmcnt(8), 1 barrier per chunk --
// all 8 waves execute identical barrier counts).
// LDS: adjS 64 KB + pT 33 KB = ~97 KB -> 1 block/CU, grid 512.
// ---------------------------------------------------------------------------
__global__ __launch_bounds__(512, 1) void k2_attn(
    const int* __restrict__ adj, const _Float16* __restrict__ whT,
    const float* __restrict__ s1, const float* __restrict__ s2,
    float* __restrict__ out)
{
    __shared__ __attribute__((aligned(16))) int adjS[2][32][256];        // 64 KB
    __shared__ __attribute__((aligned(16))) _Float16 pT[2][2][16][264];  // 33 KB
    __shared__ float lL[2][16];
    __shared__ float smaxL[8];

    int t = threadIdx.x, lane = t & 63, w = t >> 6;
    int b = blockIdx.x >> 6;
    int i0 = (blockIdx.x & 63) << 5;          // 32 rows per block
    int tile = w >> 2;                        // 0 or 1: row-tile
    int wq = w & 3;                           // role within tile (= R3's w)
    int rbase = i0 + tile * 16;               // this tile's first row

    // --- exact S2MAX over batch b (8 KB, L2-hot): 512 thr x 1 float4 ---
    const float4* s2v = (const float4*)(s2 + (size_t)b * N_);
    float4 uv = s2v[t];
    float vm = fmaxf(fmaxf(uv.x, uv.y), fmaxf(uv.z, uv.w));
    #pragma unroll
    for (int m = 32; m >= 1; m >>= 1) vm = fmaxf(vm, __shfl_xor(vm, m));
    if (lane == 0) smaxL[w] = vm;
    __syncthreads();
    float s2max = smaxL[0];
    #pragma unroll
    for (int i = 1; i < 8; ++i) s2max = fmaxf(s2max, smaxL[i]);

    int l15 = lane & 15, quad = lane >> 4;
    int f0 = wq * 16;

    // per-row folded constants (wave handles rows rbase + wq*4 .. +3)
    float c1[4], c2[4], lacc[4];
    #pragma unroll
    for (int rr = 0; rr < 4; ++rr) {
        float sv = s1[(size_t)b * N_ + rbase + wq * 4 + rr];   // wave-uniform
        float mm = sv + s2max;
        float mh = fmaxf(mm, ALPHA * mm);    // leaky(s1_i + s2max) >= row max
        c1[rr] = (sv - mh) * LOG2E;
        c2[rr] = (ALPHA * sv - mh) * LOG2E;
        lacc[rr] = 0.f;
    }

    // per-lane global bases
    const int* adjL = adj + ((size_t)b * N_ + rbase + wq * 4) * N_ + lane * 4;
    const float* s2L = s2 + (size_t)b * N_ + lane * 4;
    float4 Sb[2];

    // DMA one chunk's 4 rows (this wave's rows) + s2 reg prefetch. 5 vm ops.
#define STAGE(cn, bf) do {                                                   \
        _Pragma("unroll")                                                    \
        for (int rr = 0; rr < 4; ++rr) {                                     \
            const int* src_ = adjL + (size_t)rr * N_ + (cn) * 256;           \
            __builtin_amdgcn_global_load_lds(                                \
                (const __attribute__((address_space(1))) void*)src_,         \
                (__attribute__((address_space(3))) void*)                    \
                    &adjS[bf][tile * 16 + wq * 4 + rr][0],                   \
                16, 0, 0);                                                   \
        }                                                                    \
        Sb[bf] = *(const float4*)(s2L + (cn) * 256);                         \
    } while (0)

    STAGE(0, 0);                              // prologue: chunk 0 in flight

    float4v acc = {0.f, 0.f, 0.f, 0.f};
    const _Float16* wB = whT + ((size_t)b * FOUT + f0 + l15) * N_ + quad * 8;

    #pragma unroll
    for (int c = 0; c < 8; ++c) {
        // bf(c) into regs FIRST (older than the new stage -> compiler's
        // bf-waits never force the fresh DMA to drain)
        half8 bfr[8];
        const _Float16* wp = wB + c * 256;
        #pragma unroll
        for (int kk = 0; kk < 8; ++kk) bfr[kk] = *(const half8*)(wp + kk * 32);

        if (c < 7) {
            STAGE(c + 1, (c + 1) & 1);
            asm volatile("s_waitcnt vmcnt(13)" ::: "memory"); // drain chunk c DMA only
        } else {
            asm volatile("s_waitcnt vmcnt(8)" ::: "memory");  // leave bf(7) in flight
        }
        __builtin_amdgcn_sched_barrier(0);

        // p-compute chunk c from adjS[c&1] + Sb[c&1]
        {
            float4 sv = Sb[c & 1];
            float u[4]  = {sv.x * LOG2E, sv.y * LOG2E, sv.z * LOG2E, sv.w * LOG2E};
            float ua[4] = {u[0] * ALPHA, u[1] * ALPHA, u[2] * ALPHA, u[3] * ALPHA};
            #pragma unroll
            for (int rr = 0; rr < 4; ++rr) {
                int r = tile * 16 + wq * 4 + rr;
                int4 av = *(const int4*)&adjS[c & 1][r][lane * 4];
                int aa[4] = {av.x, av.y, av.z, av.w};
                half4 pf;
                float ls = 0.f;
                #pragma unroll
                for (int e = 0; e < 4; ++e) {
                    float tt = fmaxf(c1[rr] + u[e], c2[rr] + ua[e]);
#if __has_builtin(__builtin_amdgcn_exp2f)
                    float p = __builtin_amdgcn_exp2f(tt);
#else
                    float p = exp2f(tt);
#endif
                    p = (aa[e] > 0) ? p : 0.f;
                    ls += p;
                    pf[e] = (_Float16)p;
                }
                lacc[rr] += ls;
                *(half4*)&pT[c & 1][tile][wq * 4 + rr][lane * 4] = pf;
            }
        }

        if (c == 7) {
            // publish row sums before the last barrier
            #pragma unroll
            for (int rr = 0; rr < 4; ++rr) {
                float v = lacc[rr];
                #pragma unroll
                for (int m = 32; m >= 1; m >>= 1) v += __shfl_xor(v, m);
                if (lane == 0) lL[tile][wq * 4 + rr] = v;
            }
        }

        __syncthreads();   // publish pT[c&1]; prior-buffer readers proven done

        // MFMA on pT[c&1][tile] with reg-resident B
        #pragma unroll
        for (int kk = 0; kk < 8; ++kk) {
            half8 af = *(const half8*)&pT[c & 1][tile][l15][kk * 32 + quad * 8];
            acc = __builtin_amdgcn_mfma_f32_16x16x32_f16(af, bfr[kk], acc, 0, 0, 0);
        }
    }
#undef STAGE

    // epilogue: normalize, ELU, store. D: row=quad*4+reg, col=f0+l15
    #pragma unroll
    for (int reg = 0; reg < 4; ++reg) {
        int row = quad * 4 + reg;
        float val = acc[reg] / lL[tile][row];
        val = (val > 0.f) ? val : (__expf(val) - 1.f);   // ELU
        out[((size_t)b * N_ + rbase + row) * FOUT + f0 + l15] = val;
    }
}

// ---------------------------------------------------------------------------
extern "C" void kernel_launch(void* const* d_in, const int* in_sizes, int n_in,
                              void* d_out, int out_size, void* d_ws, size_t ws_size,
                              hipStream_t stream) {
    const float* x   = (const float*)d_in[0];
    const int*   adj = (const int*)d_in[1];
    const float* W   = (const float*)d_in[2];
    const float* w2  = (const float*)d_in[3];
    float* out = (float*)d_out;

    char* ws = (char*)d_ws;
    _Float16* whT = (_Float16*)ws;                              // 2 MiB
    float* s1  = (float*)(ws + 2097152);                        // 64 KiB
    float* s2  = (float*)(ws + 2097152 + 65536);                // 64 KiB

    k1_wh<<<(B_ * N_) / 32, 256, 0, stream>>>(x, W, w2, whT, s1, s2);
    k2_attn<<<(B_ * N_) / 32, 512, 0, stream>>>(adj, whT, s1, s2, out);
}